// Round 8
// baseline (687.642 us; speedup 1.0000x reference)
//
#include <hip/hip_runtime.h>
#include <hip/hip_bf16.h>
#include <hip/hip_fp8.h>

constexpr int kB   = 4;
constexpr int kT   = 2048;
constexpr int kCIN = 2048;
constexpr int kHID = 1024;
constexpr int kEMB = 256;

typedef __bf16 bf16_t;
typedef __bf16 bf16x8 __attribute__((ext_vector_type(8)));
typedef __bf16 bf16x4 __attribute__((ext_vector_type(4)));
typedef float  f32x4  __attribute__((ext_vector_type(4)));
typedef unsigned char u8;
typedef u8 u8x8 __attribute__((ext_vector_type(8)));
typedef u8 u8x4 __attribute__((ext_vector_type(4)));
typedef long i64_t;

__device__ __forceinline__ u8 f2fp8(float f) { return __hip_fp8_e4m3(f).__x; }

// async global->LDS 16B/lane (LDS dest = wave-uniform base + lane*16)
__device__ __forceinline__ void gll16(const void* g, void* l) {
  auto lp = reinterpret_cast<__attribute__((address_space(3))) uint32_t*>(
      reinterpret_cast<uintptr_t>(l));
  __builtin_amdgcn_global_load_lds(static_cast<const uint32_t*>(g), lp, 16, 0, 0);
}

// ============ bf16 GEMM core (unchanged structure; + output scale) ============
// MODE 0: bf16 store, 2: f32 atomicAdd.
template <int MODE>
__device__ __forceinline__ void gemm_core(bf16_t* sA, bf16_t* sB,
                                          const bf16_t* A, const bf16_t* B, void* Cv,
                                          int lda, int ldb, int ldc,
                                          int m0, int n0, int Klen,
                                          const float* biasN, float oscale) {
  const int tid = threadIdx.x;
  const int lane = tid & 63, wave = tid >> 6;
  const int wm = wave & 1, wn = wave >> 1;
  const int lm = lane & 15, q = lane >> 4;

  f32x4 acc[4][4];
#pragma unroll
  for (int i = 0; i < 4; i++)
#pragma unroll
    for (int j = 0; j < 4; j++)
#pragma unroll
      for (int r = 0; r < 4; r++) acc[i][j][r] = 0.f;

  const int srow = wave * 16 + (lane >> 2);
  const int scol = (lane & 3) * 8;
  const bf16_t* gA0 = A + (size_t)(m0 + srow) * lda + scol;
  const bf16_t* gA1 = gA0 + (size_t)64 * lda;
  const bf16_t* gB0 = B + (size_t)(n0 + srow) * ldb + scol;
  const bf16_t* gB1 = gB0 + (size_t)64 * ldb;
  bf16_t* lA0 = &sA[wave * 512];
  bf16_t* lA1 = &sA[64 * 32 + wave * 512];
  bf16_t* lB0 = &sB[wave * 512];
  bf16_t* lB1 = &sB[64 * 32 + wave * 512];

  for (int k0 = 0; k0 < Klen; k0 += 64) {
    __syncthreads();
    gll16(gA0 + k0,      lA0);
    gll16(gA0 + k0 + 32, lA0 + 4096);
    gll16(gA1 + k0,      lA1);
    gll16(gA1 + k0 + 32, lA1 + 4096);
    gll16(gB0 + k0,      lB0);
    gll16(gB0 + k0 + 32, lB0 + 4096);
    gll16(gB1 + k0,      lB1);
    gll16(gB1 + k0 + 32, lB1 + 4096);
    __syncthreads();

#pragma unroll
    for (int kk = 0; kk < 2; kk++) {
      bf16x8 af[4], bfr[4];
#pragma unroll
      for (int i = 0; i < 4; i++)
        af[i] = *(const bf16x8*)(&sA[kk * 4096 + (wm * 64 + i * 16 + lm) * 32 + q * 8]);
#pragma unroll
      for (int j = 0; j < 4; j++)
        bfr[j] = *(const bf16x8*)(&sB[kk * 4096 + (wn * 64 + j * 16 + lm) * 32 + q * 8]);
#pragma unroll
      for (int i = 0; i < 4; i++)
#pragma unroll
        for (int j = 0; j < 4; j++)
          acc[i][j] = __builtin_amdgcn_mfma_f32_16x16x32_bf16(af[i], bfr[j], acc[i][j], 0, 0, 0);
    }
  }

#pragma unroll
  for (int i = 0; i < 4; i++) {
    const int gmb = m0 + wm * 64 + i * 16 + q * 4;
#pragma unroll
    for (int j = 0; j < 4; j++) {
      const int gn = n0 + wn * 64 + j * 16 + lm;
      float bn_ = biasN ? biasN[gn] : 0.f;
#pragma unroll
      for (int r = 0; r < 4; r++) {
        const int gm = gmb + r;
        float v = (acc[i][j][r] + bn_) * oscale;
        const size_t idx = (size_t)gm * ldc + gn;
        if (MODE == 0) ((bf16_t*)Cv)[idx] = (bf16_t)v;
        else           atomicAdd(&((float*)Cv)[idx], v);
      }
    }
  }
}

// ============ fp8 GEMM core: [128][64]-byte tiles, mfma_f32_16x16x32_fp8_fp8 =====
// Same lane->k mapping as bf16 16x16x32 (k = quad*8 + byte). MODE 0: bf16 out, 1: fp8 out.
template <int MODE>
__device__ __forceinline__ void gemm_core_f8(u8* sA, u8* sB,
                                             const u8* A, const u8* B, void* Cv,
                                             int lda, int ldb, int ldc,
                                             int m0, int n0, int Klen,
                                             const float* biasN) {
  const int tid = threadIdx.x;
  const int lane = tid & 63, wave = tid >> 6;
  const int wm = wave & 1, wn = wave >> 1;
  const int lm = lane & 15, q = lane >> 4;

  f32x4 acc[4][4];
#pragma unroll
  for (int i = 0; i < 4; i++)
#pragma unroll
    for (int j = 0; j < 4; j++)
#pragma unroll
      for (int r = 0; r < 4; r++) acc[i][j][r] = 0.f;

  // staging: 16B/lane; lane i -> row (i>>2), byte-chunk (i&3)*16 of a 64B row.
  const int srow = wave * 16 + (lane >> 2);
  const int scol = (lane & 3) * 16;
  const u8* gA0 = A + (size_t)(m0 + srow) * lda + scol;
  const u8* gA1 = gA0 + (size_t)64 * lda;
  const u8* gB0 = B + (size_t)(n0 + srow) * ldb + scol;
  const u8* gB1 = gB0 + (size_t)64 * ldb;
  u8* lA0 = &sA[wave * 1024];
  u8* lA1 = &sA[4096 + wave * 1024];
  u8* lB0 = &sB[wave * 1024];
  u8* lB1 = &sB[4096 + wave * 1024];

  for (int k0 = 0; k0 < Klen; k0 += 64) {
    __syncthreads();
    gll16(gA0 + k0, lA0);
    gll16(gA1 + k0, lA1);
    gll16(gB0 + k0, lB0);
    gll16(gB1 + k0, lB1);
    __syncthreads();

#pragma unroll
    for (int kk = 0; kk < 2; kk++) {
      i64_t af[4], bfr[4];
#pragma unroll
      for (int i = 0; i < 4; i++)
        af[i] = *(const i64_t*)(&sA[(wm * 64 + i * 16 + lm) * 64 + kk * 32 + q * 8]);
#pragma unroll
      for (int j = 0; j < 4; j++)
        bfr[j] = *(const i64_t*)(&sB[(wn * 64 + j * 16 + lm) * 64 + kk * 32 + q * 8]);
#pragma unroll
      for (int i = 0; i < 4; i++)
#pragma unroll
        for (int j = 0; j < 4; j++)
          acc[i][j] = __builtin_amdgcn_mfma_f32_16x16x32_fp8_fp8(af[i], bfr[j], acc[i][j], 0, 0, 0);
    }
  }

#pragma unroll
  for (int i = 0; i < 4; i++) {
    const int gmb = m0 + wm * 64 + i * 16 + q * 4;
#pragma unroll
    for (int j = 0; j < 4; j++) {
      const int gn = n0 + wn * 64 + j * 16 + lm;
      float bn_ = biasN ? biasN[gn] : 0.f;
#pragma unroll
      for (int r = 0; r < 4; r++) {
        const int gm = gmb + r;
        float v = acc[i][j][r] + bn_;
        const size_t idx = (size_t)gm * ldc + gn;
        if (MODE == 0) ((bf16_t*)Cv)[idx] = (bf16_t)v;
        else           ((u8*)Cv)[idx] = f2fp8(v);
      }
    }
  }
}

// ============ dispatch 1: prep (casts + wwT + biases); x -> bf16 AND fp8 ==========
__global__ __launch_bounds__(256) void k_prep(const float* __restrict__ x,
                                              const float* __restrict__ th,
                                              const float* __restrict__ ph,
                                              const float* __restrict__ g,
                                              const float* __restrict__ emb,
                                              const float* __restrict__ w_w,
                                              const float* __restrict__ w_b,
                                              const float* __restrict__ emb_b,
                                              const float* __restrict__ tb,
                                              const float* __restrict__ pb,
                                              const float* __restrict__ gb,
                                              bf16_t* __restrict__ xbf,
                                              u8* __restrict__ xbf8,
                                              u8* __restrict__ wqkv8,
                                              bf16_t* __restrict__ embbf,
                                              bf16_t* __restrict__ wwT,
                                              float* __restrict__ biase,
                                              float* __restrict__ bqkv) {
  __shared__ float tile[64 * 66];
  const int b = blockIdx.x;
  if (b < 16384) {  // x -> bf16 (xe path) + fp8 (moca path)
    long i = (long)b * 256 + threadIdx.x;
    float4 v = ((const float4*)x)[i];
    bf16x4 ob; u8x4 o8;
    ob[0] = (bf16_t)v.x; ob[1] = (bf16_t)v.y; ob[2] = (bf16_t)v.z; ob[3] = (bf16_t)v.w;
    o8[0] = f2fp8(v.x); o8[1] = f2fp8(v.y); o8[2] = f2fp8(v.z); o8[3] = f2fp8(v.w);
    ((bf16x4*)xbf)[i] = ob;
    ((u8x4*)xbf8)[i] = o8;
  } else if (b < 22528) {  // theta|phi|g -> fp8 wqkv8
    const float* in; u8* out;
    if (b < 18432)      { in = th; out = wqkv8; }
    else if (b < 20480) { in = ph; out = wqkv8 + (size_t)kHID * kCIN; }
    else                { in = g;  out = wqkv8 + (size_t)2 * kHID * kCIN; }
    long i = (long)((b - 16384) & 2047) * 256 + threadIdx.x;
    float4 v = ((const float4*)in)[i];
    u8x4 o8;
    o8[0] = f2fp8(v.x); o8[1] = f2fp8(v.y); o8[2] = f2fp8(v.z); o8[3] = f2fp8(v.w);
    ((u8x4*)out)[i] = o8;
  } else if (b < 23040) {  // emb -> bf16
    long i = (long)(b - 22528) * 256 + threadIdx.x;
    float4 v = ((const float4*)emb)[i];
    bf16x4 o;
    o[0] = (bf16_t)v.x; o[1] = (bf16_t)v.y; o[2] = (bf16_t)v.z; o[3] = (bf16_t)v.w;
    ((bf16x4*)embbf)[i] = o;
  } else if (b < 23552) {  // w_w (CIN,HID) -> wwT (HID,CIN) bf16
    int j = b - 23040;
    int h0 = (j & 15) * 64, c0 = (j >> 4) * 64;
#pragma unroll
    for (int k = 0; k < 16; k++) {
      int e = k * 256 + threadIdx.x;
      int r = e >> 6, c = e & 63;
      tile[r * 66 + c] = w_w[(size_t)(c0 + r) * kHID + h0 + c];
    }
    __syncthreads();
#pragma unroll
    for (int k = 0; k < 16; k++) {
      int e = k * 256 + threadIdx.x;
      int r = e >> 6, c = e & 63;
      wwT[(size_t)(h0 + r) * kCIN + c0 + c] = (bf16_t)tile[c * 66 + r];
    }
  } else if (b < 23808) {  // bias_e
    int e = b - 23552;
    float acc = 0.f;
    for (int c = threadIdx.x; c < kCIN; c += 256)
      acc += emb[(size_t)e * kCIN + c] * w_b[c];
#pragma unroll
    for (int o = 32; o > 0; o >>= 1) acc += __shfl_xor(acc, o, 64);
    __syncthreads();
    if ((threadIdx.x & 63) == 0) tile[threadIdx.x >> 6] = acc;
    __syncthreads();
    if (threadIdx.x == 0) biase[e] = tile[0] + tile[1] + tile[2] + tile[3] + emb_b[e];
  } else {  // concat biases -> bqkv[3072]
    int i = (b - 23808) * 256 + threadIdx.x;
    if (i < 3072)
      bqkv[i] = i < 1024 ? tb[i] : (i < 2048 ? pb[i - 1024] : gb[i - 2048]);
  }
}

// ============ dispatch 2a: QKV fp8 -> xtphi8 (fp8, ld 3072) =======================
__global__ __launch_bounds__(256) void k_qkv(const u8* __restrict__ xbf8,
                                             const u8* __restrict__ wqkv8,
                                             u8* __restrict__ xtphi8,
                                             const float* __restrict__ bqkv) {
  __shared__ u8 sA[8192], sB[8192];
  gemm_core_f8<1>(sA, sB, xbf8, wqkv8, xtphi8, 2048, 2048, 3072,
                  blockIdx.x * 128, blockIdx.y * 128, 2048, bqkv);
}

// ============ dispatch 2b: S1-triangular fp8 (544) + M bf16/2048 (16) =============
__global__ __launch_bounds__(256) void k_s1m(const u8* __restrict__ xbf8,
                                             const bf16_t* __restrict__ embbf,
                                             const bf16_t* __restrict__ wwT,
                                             bf16_t* __restrict__ S1,
                                             bf16_t* __restrict__ Mbf) {
  __shared__ char smem[32768];
  const int bid = blockIdx.x;
  if (bid < 544) {  // S1[z] = x8[z] @ x8[z]^T, upper triangular tiles (nb=16)
    int z = bid / 136, t = bid % 136;
    int r = 0;
    while (t >= 16 - r) { t -= 16 - r; r++; }
    const u8* Az = xbf8 + (size_t)z * kT * kCIN;
    gemm_core_f8<0>((u8*)smem, (u8*)(smem + 8192), Az, Az,
                    S1 + (size_t)z * kT * kT, 2048, 2048, 2048,
                    r * 128, (r + t) * 128, 2048, nullptr);
  } else {  // M = (emb @ w_w) / 2048  (bf16; 1/2048 compensates moca fp8 x2048 scale)
    int m = bid - 544;
    gemm_core<0>((bf16_t*)smem, (bf16_t*)(smem + 16384), embbf, wwT, Mbf,
                 2048, 2048, 1024, (m & 1) * 128, (m >> 1) * 128, 2048,
                 nullptr, 1.f / 2048.f);
  }
}

// ==== dispatch 3: S2-fp8(1024) + mirror(1984) + xgT-fp8(2048) + zero-out(2048) ====
__global__ __launch_bounds__(256) void k_mid(const u8* __restrict__ xtphi8,
                                             bf16_t* __restrict__ S2,
                                             bf16_t* __restrict__ S1,
                                             u8* __restrict__ xgT8,
                                             float* __restrict__ out) {
  __shared__ char smem[16896];  // S2: 2x8KB fp8; mirror: bf16 64x66; xgT: u8 64x68
  const int bid = blockIdx.x;
  const size_t T2 = (size_t)kT * kT;
  if (bid < 1024) {  // S2[z] = xphi8[z] @ xt8[z]^T (K=1024, slices of xtphi8 ld 3072)
    int bm = bid & 15, bn = (bid >> 4) & 15, z = bid >> 8;
    const u8* base = xtphi8 + (size_t)z * kT * 3072;
    gemm_core_f8<0>((u8*)smem, (u8*)(smem + 8192), base + 1024, base,
                    S2 + (size_t)z * T2, 3072, 3072, 2048,
                    bm * 128, bn * 128, 1024, nullptr);
  } else if (bid < 3008) {  // mirror S1 upper -> lower (64x64 tiles, p>q)
    int j = bid - 1024;
    int z = j / 496, t = j % 496, qq = 0;
    while (t >= 31 - qq) { t -= 31 - qq; qq++; }
    int p = qq + 1 + t;
    bf16_t* tile = (bf16_t*)smem;
    const size_t base = (size_t)z * T2;
#pragma unroll
    for (int k = 0; k < 16; k++) {
      int e = k * 256 + threadIdx.x;
      int r = e >> 6, c = e & 63;
      tile[r * 66 + c] = S1[base + (size_t)(qq * 64 + r) * kT + p * 64 + c];
    }
    __syncthreads();
#pragma unroll
    for (int k = 0; k < 16; k++) {
      int e = k * 256 + threadIdx.x;
      int r = e >> 6, c = e & 63;
      S1[base + (size_t)(p * 64 + r) * kT + qq * 64 + c] = tile[c * 66 + r];
    }
  } else if (bid < 5056) {  // xgT8[z](h,t) <- transpose of xg slice (fp8)
    int j = bid - 3008;
    int hb = j & 15, tb = (j >> 4) & 31, z = j >> 9;
    u8* tile = (u8*)smem;  // [h][t] layout, stride 68
#pragma unroll
    for (int k = 0; k < 4; k++) {
      int e = k * 256 + threadIdx.x;
      int tr = e >> 4, hc = (e & 15) * 4;
      u8x4 v = *(const u8x4*)&xtphi8[(size_t)(z * kT + tb * 64 + tr) * 3072 + 2048 + hb * 64 + hc];
      tile[(hc + 0) * 68 + tr] = v[0];
      tile[(hc + 1) * 68 + tr] = v[1];
      tile[(hc + 2) * 68 + tr] = v[2];
      tile[(hc + 3) * 68 + tr] = v[3];
    }
    __syncthreads();
#pragma unroll
    for (int k = 0; k < 4; k++) {
      int e = k * 256 + threadIdx.x;
      int hr = e >> 4, tc = (e & 15) * 4;
      u8x4 v = *(const u8x4*)&tile[hr * 68 + tc];
      *(u8x4*)&xgT8[(size_t)z * kHID * kT + (size_t)(hb * 64 + hr) * kT + tb * 64 + tc] = v;
    }
  } else {  // zero d_out
    long i = (long)(bid - 5056) * 256 + threadIdx.x;
    ((float4*)out)[i] = make_float4(0.f, 0.f, 0.f, 0.f);
  }
}

// ============ dispatch 4: moca (both passes) -> fp8 x2048 =========================
__global__ __launch_bounds__(256) void k_moca(const bf16_t* __restrict__ S1,
                                              const bf16_t* __restrict__ S2,
                                              u8* __restrict__ dst8,
                                              const float* __restrict__ rou_w,
                                              const float* __restrict__ rou_b) {
  __shared__ float s[4];
  const int t = blockIdx.x, b = blockIdx.y;
  const size_t T2 = (size_t)kT * kT;
  const bf16_t* src = (b < 2) ? S1 : S2;
  const int pb = (b < 2) ? 2 * b : 2 * (b - 2);
  const bf16_t* rA = src + (size_t)pb * T2 + (size_t)t * kT;
  const bf16_t* rB = rA + T2;
  const int base = threadIdx.x * 8;

  float va[8], vb[8];
  {
    bf16x8 a = *(const bf16x8*)(rA + base);
    bf16x8 bb = *(const bf16x8*)(rB + base);
#pragma unroll
    for (int j = 0; j < 8; j++) { va[j] = (float)a[j]; vb[j] = (float)bb[j]; }
  }
  auto red_max = [&](float v) {
#pragma unroll
    for (int o = 32; o > 0; o >>= 1) v = fmaxf(v, __shfl_xor(v, o, 64));
    __syncthreads();
    if ((threadIdx.x & 63) == 0) s[threadIdx.x >> 6] = v;
    __syncthreads();
    return fmaxf(fmaxf(s[0], s[1]), fmaxf(s[2], s[3]));
  };
  auto red_sum = [&](float v) {
#pragma unroll
    for (int o = 32; o > 0; o >>= 1) v += __shfl_xor(v, o, 64);
    __syncthreads();
    if ((threadIdx.x & 63) == 0) s[threadIdx.x >> 6] = v;
    __syncthreads();
    return (s[0] + s[1]) + (s[2] + s[3]);
  };

  float m = -1e30f, acc;
#pragma unroll
  for (int j = 0; j < 8; j++) m = fmaxf(m, va[j]);
  m = red_max(m); acc = 0.f;
#pragma unroll
  for (int j = 0; j < 8; j++) { va[j] = __expf(va[j] - m); acc += va[j]; }
  float invA = 1.f / red_sum(acc);

  m = -1e30f;
#pragma unroll
  for (int j = 0; j < 8; j++) m = fmaxf(m, vb[j]);
  m = red_max(m); acc = 0.f;
#pragma unroll
  for (int j = 0; j < 8; j++) { vb[j] = __expf(vb[j] - m); acc += vb[j]; }
  float invB = 1.f / red_sum(acc);

  const float r0 = rou_w[0], r1 = rou_w[1], rb = rou_b[0];
#pragma unroll
  for (int j = 0; j < 8; j++) va[j] = r0 * va[j] * invA + r1 * vb[j] * invB + rb;

  m = -1e30f;
#pragma unroll
  for (int j = 0; j < 8; j++) m = fmaxf(m, va[j]);
  m = red_max(m); acc = 0.f;
#pragma unroll
  for (int j = 0; j < 8; j++) { va[j] = __expf(va[j] - m); acc += va[j]; }
  float invC = 2048.f / red_sum(acc);  // x2048: lift probs above fp8 subnormal floor

  u8x8 o;
#pragma unroll
  for (int j = 0; j < 8; j++) o[j] = f2fp8(va[j] * invC);
  *(u8x8*)(dst8 + (size_t)b * T2 + (size_t)t * kT + base) = o;
}

// ============ dispatch 5: mocab8 -> mocaT8 (batched TxT fp8 transpose) ============
__global__ __launch_bounds__(256) void k_mocaT(const u8* __restrict__ in,
                                               u8* __restrict__ outp) {
  __shared__ u8 tile[64 * 68];  // [c][r] layout
  const size_t base = (size_t)blockIdx.z * kT * kT;
  const int r0 = blockIdx.y * 64, c0 = blockIdx.x * 64;
#pragma unroll
  for (int k = 0; k < 4; k++) {
    int e = k * 256 + threadIdx.x;
    int r = e >> 4, cc = (e & 15) * 4;
    u8x4 v = *(const u8x4*)&in[base + (size_t)(r0 + r) * kT + c0 + cc];
    tile[(cc + 0) * 68 + r] = v[0];
    tile[(cc + 1) * 68 + r] = v[1];
    tile[(cc + 2) * 68 + r] = v[2];
    tile[(cc + 3) * 68 + r] = v[3];
  }
  __syncthreads();
#pragma unroll
  for (int k = 0; k < 4; k++) {
    int e = k * 256 + threadIdx.x;
    int c = e >> 4, rr = (e & 15) * 4;
    u8x4 v = *(const u8x4*)&tile[c * 68 + rr];
    *(u8x4*)&outp[base + (size_t)(c0 + c) * kT + r0 + rr] = v;
  }
}

// ==== dispatch 6: yT fp8 GEMM(512) + x@emb^T bf16 split-K4 atomic (512) ===========
__global__ __launch_bounds__(256) void k_tail1(const u8* __restrict__ mocaT8,
                                               const u8* __restrict__ xgT8,
                                               bf16_t* __restrict__ yT,
                                               const bf16_t* __restrict__ xbf,
                                               const bf16_t* __restrict__ embbf,
                                               float* __restrict__ out,
                                               const float* __restrict__ biase) {
  __shared__ char smem[32768];
  const int bid = blockIdx.x;
  if (bid < 512) {  // yT[z] = mocaT8[z] @ xgT8[z]^T  (2048 x 1024, K=2048) -> bf16 (x2048 scale)
    int bm = bid & 15, bn = (bid >> 4) & 7, z = bid >> 7;
    gemm_core_f8<0>((u8*)smem, (u8*)(smem + 8192),
                    mocaT8 + (size_t)z * kT * kT, xgT8 + (size_t)z * kHID * kT,
                    yT + (size_t)z * kT * kHID, 2048, 2048, 1024,
                    bm * 128, bn * 128, 2048, nullptr);
  } else {  // out += x @ emb^T slice (K=512 each), + biase on slice 0 (bf16 path)
    int r = bid - 512;
    int bm = r & 63, bn = (r >> 6) & 1, ks = r >> 7;
    gemm_core<2>((bf16_t*)smem, (bf16_t*)(smem + 16384),
                 xbf + ks * 512, embbf + ks * 512, out, 2048, 2048, 256,
                 bm * 128, bn * 128, 512, ks == 0 ? biase : nullptr, 1.f);
  }
}

// ============ dispatch 7: out += yT @ M^T split-K4 atomic (512) ===================
__global__ __launch_bounds__(256) void k_tail2(const bf16_t* __restrict__ yT,
                                               const bf16_t* __restrict__ Mbf,
                                               float* __restrict__ out) {
  __shared__ char smem[32768];
  const int bid = blockIdx.x;
  int bm = bid & 63, bn = (bid >> 6) & 1, ks = bid >> 7;
  gemm_core<2>((bf16_t*)smem, (bf16_t*)(smem + 16384),
               yT + ks * 256, Mbf + ks * 256, out, 1024, 1024, 256,
               bm * 128, bn * 128, 256, nullptr, 1.f);
}

extern "C" void kernel_launch(void* const* d_in, const int* in_sizes, int n_in,
                              void* d_out, int out_size, void* d_ws, size_t ws_size,
                              hipStream_t stream) {
  const float* x       = (const float*)d_in[0];
  const float* theta_w = (const float*)d_in[1];
  const float* theta_b = (const float*)d_in[2];
  const float* phi_w   = (const float*)d_in[3];
  const float* phi_b   = (const float*)d_in[4];
  const float* g_w     = (const float*)d_in[5];
  const float* g_b     = (const float*)d_in[6];
  const float* rou_w   = (const float*)d_in[7];
  const float* rou_b   = (const float*)d_in[8];
  const float* w_w     = (const float*)d_in[9];
  const float* w_b     = (const float*)d_in[10];
  const float* emb_w   = (const float*)d_in[11];
  const float* emb_b   = (const float*)d_in[12];
  float* out = (float*)d_out;

  char* ws = (char*)d_ws;
  size_t off = 0;
  auto alloc = [&](size_t bytes) -> char* {
    off = (off + 255) & ~(size_t)255;
    char* p = ws + off;
    off += bytes;
    return p;
  };

  const size_t BT = (size_t)kB * kT;   // 8192
  const size_t T2 = (size_t)kT * kT;   // 4M

  // ~180 MB total (< 256 MB)
  bf16_t* xbf   = (bf16_t*)alloc(BT * kCIN * 2);               // 33.5 MB (xe path)
  u8*     xbf8  = (u8*)alloc(BT * kCIN);                       // 16.8 MB (fp8 moca path)
  u8*     wqkv8 = (u8*)alloc((size_t)3 * kHID * kCIN);         // 6.3 MB
  bf16_t* embbf = (bf16_t*)alloc((size_t)kEMB * kCIN * 2);     // 1.0 MB
  bf16_t* wwT   = (bf16_t*)alloc((size_t)kHID * kCIN * 2);     // 4.2 MB
  u8*     xtphi8= (u8*)alloc(BT * 3072);                       // 25.2 MB [xt|xphi|xg] fp8
  u8*     xgT8  = (u8*)alloc((size_t)kB * kHID * kT);          // 8.4 MB
  u8*     mocab8= (u8*)alloc((size_t)kB * T2);                 // 16.8 MB (x2048-scaled)
  bf16_t* Mbf   = (bf16_t*)alloc((size_t)kEMB * kHID * 2);     // 0.5 MB (pre-scaled /2048)
  float*  biase = (float*)alloc((size_t)kEMB * 4);
  float*  bqkv  = (float*)alloc((size_t)3072 * 4);
  bf16_t* S1    = (bf16_t*)alloc((size_t)kB * T2 * 2);         // 33.5 MB
  bf16_t* S2    = (bf16_t*)alloc((size_t)kB * T2 * 2);         // 33.5 MB
  // aliases over dead regions:
  u8*     mocaT8 = (u8*)xtphi8;   // xtphi8 dead after k_mid (needs 16.8 <= 25.2)
  bf16_t* yT     = (bf16_t*)S2;   // S2 dead after k_moca (needs 16.8 <= 33.5)

  // 1: prep
  k_prep<<<dim3(23820), 256, 0, stream>>>(x, theta_w, phi_w, g_w, emb_w, w_w, w_b,
                                          emb_b, theta_b, phi_b, g_b,
                                          xbf, xbf8, wqkv8, embbf, wwT, biase, bqkv);
  // 2a: QKV fp8 (homogeneous — mega-merge regressed L2, round-6 lesson)
  k_qkv<<<dim3(64, 24), 256, 0, stream>>>(xbf8, wqkv8, xtphi8, bqkv);
  // 2b: S1-triangular fp8 + M bf16
  k_s1m<<<dim3(560), 256, 0, stream>>>(xbf8, embbf, wwT, S1, Mbf);
  // 3: S2 fp8 + mirror(S1) + xgT8 + zero(out)
  k_mid<<<dim3(7104), 256, 0, stream>>>(xtphi8, S2, S1, xgT8, out);
  // 4: moca (both passes) -> fp8 x2048
  k_moca<<<dim3(kT, kB), 256, 0, stream>>>(S1, S2, mocab8, rou_w, rou_b);
  // 5: mocaT8 (overwrites dead xtphi8)
  k_mocaT<<<dim3(32, 32, kB), 256, 0, stream>>>(mocab8, mocaT8);
  // 6: yT fp8 GEMM (over dead S2) + x@emb^T bf16 split-K atomic + biase
  k_tail1<<<dim3(1024), 256, 0, stream>>>(mocaT8, xgT8, yT, xbf, embbf, out, biase);
  // 7: out += yT @ (M/2048)^T split-K atomic (yT carries x2048)
  k_tail2<<<dim3(512), 256, 0, stream>>>(yT, Mbf, out);
}

// Round 9
// 545.343 us; speedup vs baseline: 1.2609x; 1.2609x over previous
//
#include <hip/hip_runtime.h>
#include <hip/hip_bf16.h>
#include <hip/hip_fp8.h>

constexpr int kB   = 4;
constexpr int kT   = 2048;
constexpr int kCIN = 2048;
constexpr int kHID = 1024;
constexpr int kEMB = 256;

typedef __bf16 bf16_t;
typedef __bf16 bf16x8 __attribute__((ext_vector_type(8)));
typedef __bf16 bf16x4 __attribute__((ext_vector_type(4)));
typedef float  f32x4  __attribute__((ext_vector_type(4)));
typedef unsigned char u8;
typedef u8 u8x8 __attribute__((ext_vector_type(8)));
typedef u8 u8x4 __attribute__((ext_vector_type(4)));
typedef long i64_t;

__device__ __forceinline__ u8 f2fp8(float f) { return __hip_fp8_e4m3(f).__x; }

// async global->LDS 16B/lane (LDS dest = wave-uniform base + lane*16)
__device__ __forceinline__ void gll16(const void* g, void* l) {
  auto lp = reinterpret_cast<__attribute__((address_space(3))) uint32_t*>(
      reinterpret_cast<uintptr_t>(l));
  __builtin_amdgcn_global_load_lds(static_cast<const uint32_t*>(g), lp, 16, 0, 0);
}

// ============ bf16 GEMM core (proven; + output scale) ============
// MODE 0: bf16 store, 2: f32 atomicAdd.
template <int MODE>
__device__ __forceinline__ void gemm_core(bf16_t* sA, bf16_t* sB,
                                          const bf16_t* A, const bf16_t* B, void* Cv,
                                          int lda, int ldb, int ldc,
                                          int m0, int n0, int Klen,
                                          const float* biasN, float oscale) {
  const int tid = threadIdx.x;
  const int lane = tid & 63, wave = tid >> 6;
  const int wm = wave & 1, wn = wave >> 1;
  const int lm = lane & 15, q = lane >> 4;

  f32x4 acc[4][4];
#pragma unroll
  for (int i = 0; i < 4; i++)
#pragma unroll
    for (int j = 0; j < 4; j++)
#pragma unroll
      for (int r = 0; r < 4; r++) acc[i][j][r] = 0.f;

  const int srow = wave * 16 + (lane >> 2);
  const int scol = (lane & 3) * 8;
  const bf16_t* gA0 = A + (size_t)(m0 + srow) * lda + scol;
  const bf16_t* gA1 = gA0 + (size_t)64 * lda;
  const bf16_t* gB0 = B + (size_t)(n0 + srow) * ldb + scol;
  const bf16_t* gB1 = gB0 + (size_t)64 * ldb;
  bf16_t* lA0 = &sA[wave * 512];
  bf16_t* lA1 = &sA[64 * 32 + wave * 512];
  bf16_t* lB0 = &sB[wave * 512];
  bf16_t* lB1 = &sB[64 * 32 + wave * 512];

  for (int k0 = 0; k0 < Klen; k0 += 64) {
    __syncthreads();
    gll16(gA0 + k0,      lA0);
    gll16(gA0 + k0 + 32, lA0 + 4096);
    gll16(gA1 + k0,      lA1);
    gll16(gA1 + k0 + 32, lA1 + 4096);
    gll16(gB0 + k0,      lB0);
    gll16(gB0 + k0 + 32, lB0 + 4096);
    gll16(gB1 + k0,      lB1);
    gll16(gB1 + k0 + 32, lB1 + 4096);
    __syncthreads();

#pragma unroll
    for (int kk = 0; kk < 2; kk++) {
      bf16x8 af[4], bfr[4];
#pragma unroll
      for (int i = 0; i < 4; i++)
        af[i] = *(const bf16x8*)(&sA[kk * 4096 + (wm * 64 + i * 16 + lm) * 32 + q * 8]);
#pragma unroll
      for (int j = 0; j < 4; j++)
        bfr[j] = *(const bf16x8*)(&sB[kk * 4096 + (wn * 64 + j * 16 + lm) * 32 + q * 8]);
#pragma unroll
      for (int i = 0; i < 4; i++)
#pragma unroll
        for (int j = 0; j < 4; j++)
          acc[i][j] = __builtin_amdgcn_mfma_f32_16x16x32_bf16(af[i], bfr[j], acc[i][j], 0, 0, 0);
    }
  }

#pragma unroll
  for (int i = 0; i < 4; i++) {
    const int gmb = m0 + wm * 64 + i * 16 + q * 4;
#pragma unroll
    for (int j = 0; j < 4; j++) {
      const int gn = n0 + wn * 64 + j * 16 + lm;
      float bn_ = biasN ? biasN[gn] : 0.f;
#pragma unroll
      for (int r = 0; r < 4; r++) {
        const int gm = gmb + r;
        float v = (acc[i][j][r] + bn_) * oscale;
        const size_t idx = (size_t)gm * ldc + gn;
        if (MODE == 0) ((bf16_t*)Cv)[idx] = (bf16_t)v;
        else           atomicAdd(&((float*)Cv)[idx], v);
      }
    }
  }
}

// ============ fp8 GEMM core, XOR-swizzled LDS tiles ==============================
// Tile [128][64]B; LDS slot (row, c') holds global 16B-chunk c = c' ^ (row&3).
// Fragment read for (row, kk, q): chunk (kk*2 + (q>>1)) ^ (row&3), 8B granule (q&1).
// -> each 2-bank group served by exactly 4 lanes = 4-phase structural minimum.
// MODE 0: bf16 out, 1: fp8 out.
template <int MODE>
__device__ __forceinline__ void gemm_core_f8(u8* sA, u8* sB,
                                             const u8* A, const u8* B, void* Cv,
                                             int lda, int ldb, int ldc,
                                             int m0, int n0, int Klen,
                                             const float* biasN) {
  const int tid = threadIdx.x;
  const int lane = tid & 63, wave = tid >> 6;
  const int wm = wave & 1, wn = wave >> 1;
  const int lm = lane & 15, q = lane >> 4;

  f32x4 acc[4][4];
#pragma unroll
  for (int i = 0; i < 4; i++)
#pragma unroll
    for (int j = 0; j < 4; j++)
#pragma unroll
      for (int r = 0; r < 4; r++) acc[i][j][r] = 0.f;

  // staging: lane i deposits LDS slot (row=i>>2, c'=i&3); fetch global chunk c'^(row&3)
  const int srow = wave * 16 + (lane >> 2);
  const int scol = ((lane & 3) ^ ((lane >> 2) & 3)) * 16;
  const u8* gA0 = A + (size_t)(m0 + srow) * lda + scol;
  const u8* gA1 = gA0 + (size_t)64 * lda;
  const u8* gB0 = B + (size_t)(n0 + srow) * ldb + scol;
  const u8* gB1 = gB0 + (size_t)64 * ldb;
  u8* lA0 = &sA[wave * 1024];
  u8* lA1 = &sA[4096 + wave * 1024];
  u8* lB0 = &sB[wave * 1024];
  u8* lB1 = &sB[4096 + wave * 1024];

  for (int k0 = 0; k0 < Klen; k0 += 64) {
    __syncthreads();
    gll16(gA0 + k0, lA0);
    gll16(gA1 + k0, lA1);
    gll16(gB0 + k0, lB0);
    gll16(gB1 + k0, lB1);
    __syncthreads();

#pragma unroll
    for (int kk = 0; kk < 2; kk++) {
      i64_t af[4], bfr[4];
#pragma unroll
      for (int i = 0; i < 4; i++) {
        const int ra = wm * 64 + i * 16 + lm;
        af[i] = *(const i64_t*)(&sA[ra * 64 + (((kk * 2 + (q >> 1)) ^ (ra & 3)) * 16)
                                    + (q & 1) * 8]);
      }
#pragma unroll
      for (int j = 0; j < 4; j++) {
        const int rb = wn * 64 + j * 16 + lm;
        bfr[j] = *(const i64_t*)(&sB[rb * 64 + (((kk * 2 + (q >> 1)) ^ (rb & 3)) * 16)
                                     + (q & 1) * 8]);
      }
#pragma unroll
      for (int i = 0; i < 4; i++)
#pragma unroll
        for (int j = 0; j < 4; j++)
          acc[i][j] = __builtin_amdgcn_mfma_f32_16x16x32_fp8_fp8(af[i], bfr[j], acc[i][j], 0, 0, 0);
    }
  }

#pragma unroll
  for (int i = 0; i < 4; i++) {
    const int gmb = m0 + wm * 64 + i * 16 + q * 4;
#pragma unroll
    for (int j = 0; j < 4; j++) {
      const int gn = n0 + wn * 64 + j * 16 + lm;
      float bn_ = biasN ? biasN[gn] : 0.f;
#pragma unroll
      for (int r = 0; r < 4; r++) {
        const int gm = gmb + r;
        float v = acc[i][j][r] + bn_;
        const size_t idx = (size_t)gm * ldc + gn;
        if (MODE == 0) ((bf16_t*)Cv)[idx] = (bf16_t)v;
        else           ((u8*)Cv)[idx] = f2fp8(v);
      }
    }
  }
}

// ============ dispatch 1: prep (casts + wwT + biases); x -> bf16 AND fp8 ==========
__global__ __launch_bounds__(256) void k_prep(const float* __restrict__ x,
                                              const float* __restrict__ th,
                                              const float* __restrict__ ph,
                                              const float* __restrict__ g,
                                              const float* __restrict__ emb,
                                              const float* __restrict__ w_w,
                                              const float* __restrict__ w_b,
                                              const float* __restrict__ emb_b,
                                              const float* __restrict__ tb,
                                              const float* __restrict__ pb,
                                              const float* __restrict__ gb,
                                              bf16_t* __restrict__ xbf,
                                              u8* __restrict__ xbf8,
                                              u8* __restrict__ wqkv8,
                                              bf16_t* __restrict__ embbf,
                                              bf16_t* __restrict__ wwT,
                                              float* __restrict__ biase,
                                              float* __restrict__ bqkv) {
  __shared__ float tile[64 * 66];
  const int b = blockIdx.x;
  if (b < 16384) {  // x -> bf16 (xe path) + fp8 (moca path)
    long i = (long)b * 256 + threadIdx.x;
    float4 v = ((const float4*)x)[i];
    bf16x4 ob; u8x4 o8;
    ob[0] = (bf16_t)v.x; ob[1] = (bf16_t)v.y; ob[2] = (bf16_t)v.z; ob[3] = (bf16_t)v.w;
    o8[0] = f2fp8(v.x); o8[1] = f2fp8(v.y); o8[2] = f2fp8(v.z); o8[3] = f2fp8(v.w);
    ((bf16x4*)xbf)[i] = ob;
    ((u8x4*)xbf8)[i] = o8;
  } else if (b < 22528) {  // theta|phi|g -> fp8 wqkv8
    const float* in; u8* out;
    if (b < 18432)      { in = th; out = wqkv8; }
    else if (b < 20480) { in = ph; out = wqkv8 + (size_t)kHID * kCIN; }
    else                { in = g;  out = wqkv8 + (size_t)2 * kHID * kCIN; }
    long i = (long)((b - 16384) & 2047) * 256 + threadIdx.x;
    float4 v = ((const float4*)in)[i];
    u8x4 o8;
    o8[0] = f2fp8(v.x); o8[1] = f2fp8(v.y); o8[2] = f2fp8(v.z); o8[3] = f2fp8(v.w);
    ((u8x4*)out)[i] = o8;
  } else if (b < 23040) {  // emb -> bf16
    long i = (long)(b - 22528) * 256 + threadIdx.x;
    float4 v = ((const float4*)emb)[i];
    bf16x4 o;
    o[0] = (bf16_t)v.x; o[1] = (bf16_t)v.y; o[2] = (bf16_t)v.z; o[3] = (bf16_t)v.w;
    ((bf16x4*)embbf)[i] = o;
  } else if (b < 23552) {  // w_w (CIN,HID) -> wwT (HID,CIN) bf16
    int j = b - 23040;
    int h0 = (j & 15) * 64, c0 = (j >> 4) * 64;
#pragma unroll
    for (int k = 0; k < 16; k++) {
      int e = k * 256 + threadIdx.x;
      int r = e >> 6, c = e & 63;
      tile[r * 66 + c] = w_w[(size_t)(c0 + r) * kHID + h0 + c];
    }
    __syncthreads();
#pragma unroll
    for (int k = 0; k < 16; k++) {
      int e = k * 256 + threadIdx.x;
      int r = e >> 6, c = e & 63;
      wwT[(size_t)(h0 + r) * kCIN + c0 + c] = (bf16_t)tile[c * 66 + r];
    }
  } else if (b < 23808) {  // bias_e
    int e = b - 23552;
    float acc = 0.f;
    for (int c = threadIdx.x; c < kCIN; c += 256)
      acc += emb[(size_t)e * kCIN + c] * w_b[c];
#pragma unroll
    for (int o = 32; o > 0; o >>= 1) acc += __shfl_xor(acc, o, 64);
    __syncthreads();
    if ((threadIdx.x & 63) == 0) tile[threadIdx.x >> 6] = acc;
    __syncthreads();
    if (threadIdx.x == 0) biase[e] = tile[0] + tile[1] + tile[2] + tile[3] + emb_b[e];
  } else {  // concat biases -> bqkv[3072]
    int i = (b - 23808) * 256 + threadIdx.x;
    if (i < 3072)
      bqkv[i] = i < 1024 ? tb[i] : (i < 2048 ? pb[i - 1024] : gb[i - 2048]);
  }
}

// ============ dispatch 2a: QKV fp8 -> xtphi8 (fp8, ld 3072) =======================
__global__ __launch_bounds__(256) void k_qkv(const u8* __restrict__ xbf8,
                                             const u8* __restrict__ wqkv8,
                                             u8* __restrict__ xtphi8,
                                             const float* __restrict__ bqkv) {
  __shared__ u8 sA[8192], sB[8192];
  gemm_core_f8<1>(sA, sB, xbf8, wqkv8, xtphi8, 2048, 2048, 3072,
                  blockIdx.x * 128, blockIdx.y * 128, 2048, bqkv);
}

// ============ dispatch 2b: S1-triangular fp8 (544) + M bf16/2048 (16) =============
__global__ __launch_bounds__(256) void k_s1m(const u8* __restrict__ xbf8,
                                             const bf16_t* __restrict__ embbf,
                                             const bf16_t* __restrict__ wwT,
                                             bf16_t* __restrict__ S1,
                                             bf16_t* __restrict__ Mbf) {
  __shared__ char smem[32768];
  const int bid = blockIdx.x;
  if (bid < 544) {  // S1[z] = x8[z] @ x8[z]^T, upper triangular tiles (nb=16)
    int z = bid / 136, t = bid % 136;
    int r = 0;
    while (t >= 16 - r) { t -= 16 - r; r++; }
    const u8* Az = xbf8 + (size_t)z * kT * kCIN;
    gemm_core_f8<0>((u8*)smem, (u8*)(smem + 8192), Az, Az,
                    S1 + (size_t)z * kT * kT, 2048, 2048, 2048,
                    r * 128, (r + t) * 128, 2048, nullptr);
  } else {  // M = (emb @ w_w) / 2048  (1/2048 compensates moca fp8 x2048 scale)
    int m = bid - 544;
    gemm_core<0>((bf16_t*)smem, (bf16_t*)(smem + 16384), embbf, wwT, Mbf,
                 2048, 2048, 1024, (m & 1) * 128, (m >> 1) * 128, 2048,
                 nullptr, 1.f / 2048.f);
  }
}

// ==== dispatch 3: S2-fp8(1024) + mirror(1984) + xgT-fp8(2048) + zero-out(2048) ====
__global__ __launch_bounds__(256) void k_mid(const u8* __restrict__ xtphi8,
                                             bf16_t* __restrict__ S2,
                                             bf16_t* __restrict__ S1,
                                             u8* __restrict__ xgT8,
                                             float* __restrict__ out) {
  __shared__ char smem[16896];
  const int bid = blockIdx.x;
  const size_t T2 = (size_t)kT * kT;
  if (bid < 1024) {  // S2[z] = xphi8[z] @ xt8[z]^T (K=1024, slices of xtphi8 ld 3072)
    int bm = bid & 15, bn = (bid >> 4) & 15, z = bid >> 8;
    const u8* base = xtphi8 + (size_t)z * kT * 3072;
    gemm_core_f8<0>((u8*)smem, (u8*)(smem + 8192), base + 1024, base,
                    S2 + (size_t)z * T2, 3072, 3072, 2048,
                    bm * 128, bn * 128, 1024, nullptr);
  } else if (bid < 3008) {  // mirror S1 upper -> lower (64x64 tiles, p>q)
    int j = bid - 1024;
    int z = j / 496, t = j % 496, qq = 0;
    while (t >= 31 - qq) { t -= 31 - qq; qq++; }
    int p = qq + 1 + t;
    bf16_t* tile = (bf16_t*)smem;
    const size_t base = (size_t)z * T2;
#pragma unroll
    for (int k = 0; k < 16; k++) {
      int e = k * 256 + threadIdx.x;
      int r = e >> 6, c = e & 63;
      tile[r * 66 + c] = S1[base + (size_t)(qq * 64 + r) * kT + p * 64 + c];
    }
    __syncthreads();
#pragma unroll
    for (int k = 0; k < 16; k++) {
      int e = k * 256 + threadIdx.x;
      int r = e >> 6, c = e & 63;
      S1[base + (size_t)(p * 64 + r) * kT + qq * 64 + c] = tile[c * 66 + r];
    }
  } else if (bid < 5056) {  // xgT8[z](h,t) <- transpose of xg slice (fp8)
    int j = bid - 3008;
    int hb = j & 15, tb = (j >> 4) & 31, z = j >> 9;
    u8* tile = (u8*)smem;  // [h][t] layout, stride 68
#pragma unroll
    for (int k = 0; k < 4; k++) {
      int e = k * 256 + threadIdx.x;
      int tr = e >> 4, hc = (e & 15) * 4;
      u8x4 v = *(const u8x4*)&xtphi8[(size_t)(z * kT + tb * 64 + tr) * 3072 + 2048 + hb * 64 + hc];
      tile[(hc + 0) * 68 + tr] = v[0];
      tile[(hc + 1) * 68 + tr] = v[1];
      tile[(hc + 2) * 68 + tr] = v[2];
      tile[(hc + 3) * 68 + tr] = v[3];
    }
    __syncthreads();
#pragma unroll
    for (int k = 0; k < 4; k++) {
      int e = k * 256 + threadIdx.x;
      int hr = e >> 4, tc = (e & 15) * 4;
      u8x4 v = *(const u8x4*)&tile[hr * 68 + tc];
      *(u8x4*)&xgT8[(size_t)z * kHID * kT + (size_t)(hb * 64 + hr) * kT + tb * 64 + tc] = v;
    }
  } else {  // zero d_out
    long i = (long)(bid - 5056) * 256 + threadIdx.x;
    ((float4*)out)[i] = make_float4(0.f, 0.f, 0.f, 0.f);
  }
}

// ============ dispatch 4: moca (both passes) -> fp8 x2048 =========================
__global__ __launch_bounds__(256) void k_moca(const bf16_t* __restrict__ S1,
                                              const bf16_t* __restrict__ S2,
                                              u8* __restrict__ dst8,
                                              const float* __restrict__ rou_w,
                                              const float* __restrict__ rou_b) {
  __shared__ float s[4];
  const int t = blockIdx.x, b = blockIdx.y;
  const size_t T2 = (size_t)kT * kT;
  const bf16_t* src = (b < 2) ? S1 : S2;
  const int pb = (b < 2) ? 2 * b : 2 * (b - 2);
  const bf16_t* rA = src + (size_t)pb * T2 + (size_t)t * kT;
  const bf16_t* rB = rA + T2;
  const int base = threadIdx.x * 8;

  float va[8], vb[8];
  {
    bf16x8 a = *(const bf16x8*)(rA + base);
    bf16x8 bb = *(const bf16x8*)(rB + base);
#pragma unroll
    for (int j = 0; j < 8; j++) { va[j] = (float)a[j]; vb[j] = (float)bb[j]; }
  }
  auto red_max = [&](float v) {
#pragma unroll
    for (int o = 32; o > 0; o >>= 1) v = fmaxf(v, __shfl_xor(v, o, 64));
    __syncthreads();
    if ((threadIdx.x & 63) == 0) s[threadIdx.x >> 6] = v;
    __syncthreads();
    return fmaxf(fmaxf(s[0], s[1]), fmaxf(s[2], s[3]));
  };
  auto red_sum = [&](float v) {
#pragma unroll
    for (int o = 32; o > 0; o >>= 1) v += __shfl_xor(v, o, 64);
    __syncthreads();
    if ((threadIdx.x & 63) == 0) s[threadIdx.x >> 6] = v;
    __syncthreads();
    return (s[0] + s[1]) + (s[2] + s[3]);
  };

  float m = -1e30f, acc;
#pragma unroll
  for (int j = 0; j < 8; j++) m = fmaxf(m, va[j]);
  m = red_max(m); acc = 0.f;
#pragma unroll
  for (int j = 0; j < 8; j++) { va[j] = __expf(va[j] - m); acc += va[j]; }
  float invA = 1.f / red_sum(acc);

  m = -1e30f;
#pragma unroll
  for (int j = 0; j < 8; j++) m = fmaxf(m, vb[j]);
  m = red_max(m); acc = 0.f;
#pragma unroll
  for (int j = 0; j < 8; j++) { vb[j] = __expf(vb[j] - m); acc += vb[j]; }
  float invB = 1.f / red_sum(acc);

  const float r0 = rou_w[0], r1 = rou_w[1], rb = rou_b[0];
#pragma unroll
  for (int j = 0; j < 8; j++) va[j] = r0 * va[j] * invA + r1 * vb[j] * invB + rb;

  m = -1e30f;
#pragma unroll
  for (int j = 0; j < 8; j++) m = fmaxf(m, va[j]);
  m = red_max(m); acc = 0.f;
#pragma unroll
  for (int j = 0; j < 8; j++) { va[j] = __expf(va[j] - m); acc += va[j]; }
  float invC = 2048.f / red_sum(acc);  // x2048: lift probs above fp8 subnormal floor

  u8x8 o;
#pragma unroll
  for (int j = 0; j < 8; j++) o[j] = f2fp8(va[j] * invC);
  *(u8x8*)(dst8 + (size_t)b * T2 + (size_t)t * kT + base) = o;
}

// ============ dispatch 5: mocab8 -> mocaT8 (batched TxT fp8 transpose) ============
__global__ __launch_bounds__(256) void k_mocaT(const u8* __restrict__ in,
                                               u8* __restrict__ outp) {
  __shared__ u8 tile[64 * 68];  // [c][r] layout
  const size_t base = (size_t)blockIdx.z * kT * kT;
  const int r0 = blockIdx.y * 64, c0 = blockIdx.x * 64;
#pragma unroll
  for (int k = 0; k < 4; k++) {
    int e = k * 256 + threadIdx.x;
    int r = e >> 4, cc = (e & 15) * 4;
    u8x4 v = *(const u8x4*)&in[base + (size_t)(r0 + r) * kT + c0 + cc];
    tile[(cc + 0) * 68 + r] = v[0];
    tile[(cc + 1) * 68 + r] = v[1];
    tile[(cc + 2) * 68 + r] = v[2];
    tile[(cc + 3) * 68 + r] = v[3];
  }
  __syncthreads();
#pragma unroll
  for (int k = 0; k < 4; k++) {
    int e = k * 256 + threadIdx.x;
    int c = e >> 4, rr = (e & 15) * 4;
    u8x4 v = *(const u8x4*)&tile[c * 68 + rr];
    *(u8x4*)&outp[base + (size_t)(c0 + c) * kT + r0 + rr] = v;
  }
}

// ==== dispatch 6: yT fp8 GEMM(512) + x@emb^T bf16 split-K4 atomic (512) ===========
__global__ __launch_bounds__(256) void k_tail1(const u8* __restrict__ mocaT8,
                                               const u8* __restrict__ xgT8,
                                               bf16_t* __restrict__ yT,
                                               const bf16_t* __restrict__ xbf,
                                               const bf16_t* __restrict__ embbf,
                                               float* __restrict__ out,
                                               const float* __restrict__ biase) {
  __shared__ char smem[32768];
  const int bid = blockIdx.x;
  if (bid < 512) {  // yT[z] = mocaT8[z] @ xgT8[z]^T (2048x1024, K=2048) -> bf16 (x2048)
    int bm = bid & 15, bn = (bid >> 4) & 7, z = bid >> 7;
    gemm_core_f8<0>((u8*)smem, (u8*)(smem + 8192),
                    mocaT8 + (size_t)z * kT * kT, xgT8 + (size_t)z * kHID * kT,
                    yT + (size_t)z * kT * kHID, 2048, 2048, 1024,
                    bm * 128, bn * 128, 2048, nullptr);
  } else {  // out += x @ emb^T slice (K=512 each), + biase on slice 0 (bf16 path)
    int r = bid - 512;
    int bm = r & 63, bn = (r >> 6) & 1, ks = r >> 7;
    gemm_core<2>((bf16_t*)smem, (bf16_t*)(smem + 16384),
                 xbf + ks * 512, embbf + ks * 512, out, 2048, 2048, 256,
                 bm * 128, bn * 128, 512, ks == 0 ? biase : nullptr, 1.f);
  }
}

// ============ dispatch 7: out += yT @ M^T split-K4 atomic (512) ===================
__global__ __launch_bounds__(256) void k_tail2(const bf16_t* __restrict__ yT,
                                               const bf16_t* __restrict__ Mbf,
                                               float* __restrict__ out) {
  __shared__ char smem[32768];
  const int bid = blockIdx.x;
  int bm = bid & 63, bn = (bid >> 6) & 1, ks = bid >> 7;
  gemm_core<2>((bf16_t*)smem, (bf16_t*)(smem + 16384),
               yT + ks * 256, Mbf + ks * 256, out, 1024, 1024, 256,
               bm * 128, bn * 128, 256, nullptr, 1.f);
}

extern "C" void kernel_launch(void* const* d_in, const int* in_sizes, int n_in,
                              void* d_out, int out_size, void* d_ws, size_t ws_size,
                              hipStream_t stream) {
  const float* x       = (const float*)d_in[0];
  const float* theta_w = (const float*)d_in[1];
  const float* theta_b = (const float*)d_in[2];
  const float* phi_w   = (const float*)d_in[3];
  const float* phi_b   = (const float*)d_in[4];
  const float* g_w     = (const float*)d_in[5];
  const float* g_b     = (const float*)d_in[6];
  const float* rou_w   = (const float*)d_in[7];
  const float* rou_b   = (const float*)d_in[8];
  const float* w_w     = (const float*)d_in[9];
  const float* w_b     = (const float*)d_in[10];
  const float* emb_w   = (const float*)d_in[11];
  const float* emb_b   = (const float*)d_in[12];
  float* out = (float*)d_out;

  char* ws = (char*)d_ws;
  size_t off = 0;
  auto alloc = [&](size_t bytes) -> char* {
    off = (off + 255) & ~(size_t)255;
    char* p = ws + off;
    off += bytes;
    return p;
  };

  const size_t BT = (size_t)kB * kT;   // 8192
  const size_t T2 = (size_t)kT * kT;   // 4M

  // ~180 MB total (< 256 MB)
  bf16_t* xbf   = (bf16_t*)alloc(BT * kCIN * 2);               // 33.5 MB (xe path)
  u8*     xbf8  = (u8*)alloc(BT * kCIN);                       // 16.8 MB (fp8 moca path)
  u8*     wqkv8 = (u8*)alloc((size_t)3 * kHID * kCIN);         // 6.3 MB
  bf16_t* embbf = (bf16_t*)alloc((size_t)kEMB * kCIN * 2);     // 1.0 MB
  bf16_t* wwT   = (bf16_t*)alloc((size_t)kHID * kCIN * 2);     // 4.2 MB
  u8*     xtphi8= (u8*)alloc(BT * 3072);                       // 25.2 MB [xt|xphi|xg] fp8
  u8*     xgT8  = (u8*)alloc((size_t)kB * kHID * kT);          // 8.4 MB
  u8*     mocab8= (u8*)alloc((size_t)kB * T2);                 // 16.8 MB (x2048-scaled)
  bf16_t* Mbf   = (bf16_t*)alloc((size_t)kEMB * kHID * 2);     // 0.5 MB (pre-scaled /2048)
  float*  biase = (float*)alloc((size_t)kEMB * 4);
  float*  bqkv  = (float*)alloc((size_t)3072 * 4);
  bf16_t* S1    = (bf16_t*)alloc((size_t)kB * T2 * 2);         // 33.5 MB
  bf16_t* S2    = (bf16_t*)alloc((size_t)kB * T2 * 2);         // 33.5 MB
  // aliases over dead regions:
  u8*     mocaT8 = (u8*)xtphi8;   // xtphi8 dead after k_mid (needs 16.8 <= 25.2)
  bf16_t* yT     = (bf16_t*)S2;   // S2 dead after k_moca (needs 16.8 <= 33.5)

  // 1: prep
  k_prep<<<dim3(23820), 256, 0, stream>>>(x, theta_w, phi_w, g_w, emb_w, w_w, w_b,
                                          emb_b, theta_b, phi_b, g_b,
                                          xbf, xbf8, wqkv8, embbf, wwT, biase, bqkv);
  // 2a: QKV fp8 (homogeneous; swizzled LDS)
  k_qkv<<<dim3(64, 24), 256, 0, stream>>>(xbf8, wqkv8, xtphi8, bqkv);
  // 2b: S1-triangular fp8 + M bf16
  k_s1m<<<dim3(560), 256, 0, stream>>>(xbf8, embbf, wwT, S1, Mbf);
  // 3: S2 fp8 + mirror(S1) + xgT8 + zero(out)
  k_mid<<<dim3(7104), 256, 0, stream>>>(xtphi8, S2, S1, xgT8, out);
  // 4: moca (both passes) -> fp8 x2048
  k_moca<<<dim3(kT, kB), 256, 0, stream>>>(S1, S2, mocab8, rou_w, rou_b);
  // 5: mocaT8 (overwrites dead xtphi8)
  k_mocaT<<<dim3(32, 32, kB), 256, 0, stream>>>(mocab8, mocaT8);
  // 6: yT fp8 GEMM (over dead S2) + x@emb^T bf16 split-K atomic + biase
  k_tail1<<<dim3(1024), 256, 0, stream>>>(mocaT8, xgT8, yT, xbf, embbf, out, biase);
  // 7: out += yT @ (M/2048)^T split-K atomic (yT carries x2048)
  k_tail2<<<dim3(512), 256, 0, stream>>>(yT, Mbf, out);
}